// Round 7
// baseline (277.085 us; speedup 1.0000x reference)
//
#include <hip/hip_runtime.h>
#include <math.h>

// Problem dims
constexpr int B_  = 4;
constexpr int T_  = 16;
constexpr int CIN = 32;
constexpr int HID = 64;
constexpr int HH  = 64;
constexpr int WW  = 64;
constexpr int HW  = HH * WW; // 4096

// ---------------- MFMA path config ----------------
constexpr int TR = 8,  TC = 16;         // output pixel tile: 8 rows x 16 cols
constexpr int PR = TR + 2, PC = TC + 2; // 10 x 18 (halo)
constexpr int CSL = 36;                 // channel slots per pixel (72B, 32 used)
constexpr int KCH = 32;                 // channels per K-chunk
// A slab (per chunk, per hg): [gate3][g36 = tap*4+kl][row16] 16B granules
constexpr int ASLAB_HW  = 3 * 36 * 16 * 8;            // 13824 halfwords (27648 B)
constexpr int A_GRAN    = ASLAB_HW / 8;               // 1728 granules
constexpr int ATOTAL    = 12 * ASLAB_HW;              // all slabs
constexpr int TIN_HW    = PR * PC * CSL;              // 6480 halfwords (12960 B)
constexpr int TIN_GRAN  = TIN_HW / 8;                 // 810 granules
constexpr int ROW_HW    = 66 * CSL;                   // 2376 hw per padded image row
constexpr int PIMG_HW   = 66 * ROW_HW;                // 156816 hw per padded image

// ws layout (halfword offsets)
constexpr size_t A2_HW    = (size_t)ATOTAL;               // 165888
constexpr size_t XT_OFF   = A2_HW;
constexpr size_t XT_HW    = (size_t)64 * PIMG_HW;         // 10,036,224
constexpr size_t HT_OFF   = XT_OFF + XT_HW;
constexpr size_t HTBUF_HW = (size_t)8 * PIMG_HW;          // [b4][chunk2] images
constexpr size_t WS_NEED_BYTES = (A2_HW + XT_HW + 2 * HTBUF_HW) * 2;

typedef __attribute__((ext_vector_type(8))) short bf16x8;
typedef __attribute__((ext_vector_type(4))) float f32x4;

#define GLOAD_LDS16(gsrc, ldst) \
  __builtin_amdgcn_global_load_lds((const __attribute__((address_space(1))) void*)(gsrc), \
                                   (__attribute__((address_space(3))) void*)(ldst), 16, 0, 0)

__device__ inline unsigned short f2bf(float f) {
    union { float f; unsigned u; } v; v.f = f;
    return (unsigned short)((v.u + 0x7FFFu + ((v.u >> 16) & 1u)) >> 16);
}
__device__ inline float bf2f(unsigned short h) {
    union { unsigned u; float f; } v; v.u = (unsigned)h << 16; return v.f;
}

// ---- prepass 1: weights -> bf16, transposed granules [ch][hg][gate][tap*4+kl][row16] ----
__global__ void wconv(const float* __restrict__ Wi, const float* __restrict__ Wh,
                      unsigned short* __restrict__ A2) {
    int idx = blockIdx.x * 256 + threadIdx.x;
    if (idx >= ATOTAL) return;
    int ic  = idx & 31;
    int r1  = idx >> 5;
    int tap = r1 % 9;
    int r2  = r1 / 9;
    int m   = r2 & 15;
    int r3  = r2 >> 4;
    int gt  = r3 % 3;
    int r4  = r3 / 3;
    int hg  = r4 & 3;
    int ch  = r4 >> 2;
    int o   = gt * 64 + hg * 16 + m;
    float w = (ch == 0) ? Wi[(o * CIN + ic) * 9 + tap]
                        : Wh[(o * HID + (ch - 1) * 32 + ic) * 9 + tap];
    size_t dst = (size_t)(ch * 4 + hg) * ASLAB_HW
               + ((size_t)(gt * 36 + tap * 4 + (ic >> 3)) * 16 + m) * 8 + (ic & 7);
    A2[dst] = f2bf(w);
}

// ---- prepass 2: x -> channel-last padded bf16 xT[bt][66][66][36] (coalesced) ----
__global__ void xfill(const float* __restrict__ x, unsigned short* __restrict__ xT) {
    const int riT = blockIdx.x;   // 0..65
    const int bt  = blockIdx.y;   // 0..63
    unsigned short* dst = xT + (size_t)bt * PIMG_HW + (size_t)riT * ROW_HW;
    __shared__ float lds[64 * 41];

    const bool interior = (riT >= 1 && riT <= 64);
    if (interior) {
        const float* src = x + (size_t)bt * 32 * HW + (riT - 1) * WW;
        const int p = threadIdx.x & 63;
        #pragma unroll
        for (int j = 0; j < 8; ++j) {
            int c = j * 4 + (threadIdx.x >> 6);
            lds[p * 41 + c] = src[c * HW + p];   // coalesced 256B reads
        }
    }
    __syncthreads();
    for (int g = threadIdx.x; g < ROW_HW / 8; g += 256) {   // 297 granules
        bf16x8 vv;
        #pragma unroll
        for (int k = 0; k < 8; ++k) {
            int off = g * 8 + k;
            int px = off / CSL, slot = off - px * CSL;
            float v = 0.f;
            if (interior && slot < 32 && px >= 1 && px <= 64)
                v = lds[(px - 1) * 41 + slot];
            vv[k] = (short)f2bf(v);
        }
        *(bf16x8*)(dst + g * 8) = vv;                        // coalesced 16B writes
    }
}

// ---- prepass 3: zero both hT buffers ----
__global__ void hzero(unsigned short* __restrict__ hT, int n16) {
    int i = blockIdx.x * 256 + threadIdx.x;
    if (i < n16) ((f32x4*)hT)[i] = f32x4{0.f, 0.f, 0.f, 0.f};
}

// ---- fused ConvGRU step (MFMA, DMA staging, 1 barrier/chunk) ----
// grid (32 tiles, 4 hg, 4 b), 256 thr (4 waves; wave w owns output rows 2w,2w+1)
__global__ __launch_bounds__(256, 2) void convgru_mfma(
    const unsigned short* __restrict__ xT,   // [64][66][66][36]
    const unsigned short* __restrict__ A2,   // transposed slabs
    const unsigned short* __restrict__ hTrd, // [b][chunk][66][66][36] (t-1)
    unsigned short* __restrict__ hTwr,       // same layout (t)
    float* __restrict__ out, int t)
{
    __shared__ __align__(16) unsigned short tin[2][TIN_HW];  // 2 x 12960 B
    __shared__ __align__(16) unsigned short Al[2][ASLAB_HW]; // 2 x 27648 B

    const int tid  = threadIdx.x;
    const int lane = tid & 63, wave = tid >> 6;
    const int px   = lane & 15, kl = lane >> 4;  // px = A row = B col = C col
    const int ty = blockIdx.x >> 2, tx = blockIdx.x & 3;
    const int hg = blockIdx.y, b = blockIdx.z;
    const int gy0 = ty * TR, gx0 = tx * TC;

    const int nch = (t > 0) ? 3 : 1;
    const unsigned short* xs = xT + (size_t)(b * T_ + t) * PIMG_HW;

    f32x4 accR[2] = {}, accZ[2] = {}, accNX[2] = {}, accNH[2] = {};

    // tile-origin pixel index inside a padded image (halo origin)
    const int rowbase = gy0 * 66 + gx0;

    auto stage_tin = [&](int ch, int buf) {
        const unsigned short* src = (ch == 0)
            ? xs : (hTrd + (size_t)(b * 2 + (ch - 1)) * PIMG_HW);
        #pragma unroll
        for (int j = 0; j < 4; ++j) {
            int G = tid + j * 256;
            if (G < TIN_GRAN) {
                int r = G / 81, w = G - 81 * r;   // 81 granules per halo row (18px*36hw)
                GLOAD_LDS16(src + (size_t)(rowbase + r * 66) * CSL + w * 8,
                            &tin[buf][G * 8]);
            }
        }
    };
    auto stage_A = [&](int ch, int buf) {
        const unsigned short* s = A2 + (size_t)(ch * 4 + hg) * ASLAB_HW;
        #pragma unroll
        for (int j = 0; j < 7; ++j) {
            int v = tid + j * 256;
            if (v < A_GRAN) GLOAD_LDS16(s + v * 8, &Al[buf][v * 8]);
        }
    };

    // B-frag read bases (halfword): pixel (r,c) at (r*18+c)*36
    const int rb0 = ((wave * 2 + 0) * PC + px) * CSL + kl * 8;
    const int rb1 = rb0 + PC * CSL;
    const int aoff = (kl * 16 + px) * 8;   // lane's granule offset within a gate/tap block

    auto compute = [&](int buf, bool isX) {
        const unsigned short* tb = tin[buf];
        const unsigned short* ab = Al[buf] + aoff;
        __builtin_amdgcn_s_setprio(1);
        #pragma unroll
        for (int tap = 0; tap < 9; ++tap) {
            const int dy = tap / 3, dx = tap - 3 * dy;
            const int toff = (dy * PC + dx) * CSL;
            bf16x8 b0 = *(const bf16x8*)(tb + rb0 + toff);
            bf16x8 b1 = *(const bf16x8*)(tb + rb1 + toff);
            bf16x8 ar = *(const bf16x8*)(ab + tap * 512);
            bf16x8 az = *(const bf16x8*)(ab + tap * 512 + 4608);   // +gate stride 576 gran
            bf16x8 an = *(const bf16x8*)(ab + tap * 512 + 9216);
            accR[0] = __builtin_amdgcn_mfma_f32_16x16x32_bf16(ar, b0, accR[0], 0, 0, 0);
            accR[1] = __builtin_amdgcn_mfma_f32_16x16x32_bf16(ar, b1, accR[1], 0, 0, 0);
            accZ[0] = __builtin_amdgcn_mfma_f32_16x16x32_bf16(az, b0, accZ[0], 0, 0, 0);
            accZ[1] = __builtin_amdgcn_mfma_f32_16x16x32_bf16(az, b1, accZ[1], 0, 0, 0);
            if (isX) {
                accNX[0] = __builtin_amdgcn_mfma_f32_16x16x32_bf16(an, b0, accNX[0], 0, 0, 0);
                accNX[1] = __builtin_amdgcn_mfma_f32_16x16x32_bf16(an, b1, accNX[1], 0, 0, 0);
            } else {
                accNH[0] = __builtin_amdgcn_mfma_f32_16x16x32_bf16(an, b0, accNH[0], 0, 0, 0);
                accNH[1] = __builtin_amdgcn_mfma_f32_16x16x32_bf16(an, b1, accNH[1], 0, 0, 0);
            }
        }
        __builtin_amdgcn_s_setprio(0);
    };

    // ---- pipeline: one barrier per chunk; tin & A double-buffered ----
    stage_tin(0, 0); stage_A(0, 0);
    __syncthreads();                       // compiler drains vmcnt before barrier
    for (int ch = 0; ch < nch; ++ch) {
        if (ch + 1 < nch) { stage_tin(ch + 1, (ch + 1) & 1); stage_A(ch + 1, (ch + 1) & 1); }
        compute(ch & 1, ch == 0);
        __syncthreads();
    }

    // ---- epilogue: gates + state update; h_prev (bf16) comes from retained LDS tin ----
    // chunk1 (h ch 0-31) lives in tin[1]; chunk2 (h ch 32-63) in tin[0]
    float* outp = out + ((size_t)(b * T_ + t)) * HID * HW;
    const int c0   = hg * 16 + kl * 4;
    const int slot = c0 & 31;
    const int hbuf = (hg < 2) ? 1 : 0;
    #pragma unroll
    for (int g = 0; g < 2; ++g) {
        int gy = gy0 + wave * 2 + g;
        int gx = gx0 + px;
        float hvf[4] = {0.f, 0.f, 0.f, 0.f};
        if (t > 0) {
            const unsigned short* hp =
                &tin[hbuf][((wave * 2 + g + 1) * PC + (px + 1)) * CSL + slot];
            #pragma unroll
            for (int q = 0; q < 4; ++q) hvf[q] = bf2f(hp[q]);
        }
        unsigned short hvals[4];
        #pragma unroll
        for (int q = 0; q < 4; ++q) {
            int c = c0 + q;
            float sr = 1.f / (1.f + expf(-accR[g][q]));
            float sz = 1.f / (1.f + expf(-accZ[g][q]));
            float nn = tanhf(accNX[g][q] + sr * accNH[g][q]);
            float hn = (1.f - sz) * nn + sz * hvf[q];
            outp[(size_t)c * HW + gy * WW + gx] = hn;
            hvals[q] = f2bf(hn);
        }
        unsigned short* hd = hTwr + (size_t)(b * 2 + (c0 >> 5)) * PIMG_HW
                           + (size_t)((gy + 1) * 66 + (gx + 1)) * CSL + slot;
        *(uint2*)hd = *(const uint2*)hvals;
    }
}

// ================= round-4 fallback (known-pass, tiny ws) =================
constexpr int F_AROWB = 640;
constexpr int R4_ASLAB = 48 * 9 * KCH;
constexpr int R4_AVEC  = R4_ASLAB / 8;
constexpr int R4_ATOT  = 12 * R4_ASLAB;
__global__ void wconv_r4(const float* __restrict__ Wi, const float* __restrict__ Wh,
                         unsigned short* __restrict__ A2) {
    int idx = blockIdx.x * 256 + threadIdx.x;
    if (idx >= R4_ATOT) return;
    int ic = idx & 31; int r1 = idx >> 5;
    int tap = r1 % 9; int r2 = r1 / 9;
    int m = r2 & 15; int r3 = r2 >> 4;
    int gt = r3 % 3; int r4 = r3 / 3;
    int hg = r4 & 3; int ch = r4 >> 2;
    int o = gt * 64 + hg * 16 + m;
    float w = (ch == 0) ? Wi[(o * CIN + ic) * 9 + tap]
                        : Wh[(o * HID + (ch - 1) * 32 + ic) * 9 + tap];
    A2[idx] = f2bf(w);
}
__global__ __launch_bounds__(256, 2) void convgru_r4(
    const float* __restrict__ x, const unsigned short* __restrict__ A2,
    const float* hall, float* out, int t)
{
    __shared__ __align__(16) unsigned short tin[PR * PC * 40];
    __shared__ __align__(16) unsigned short Alr[48 * (F_AROWB / 2)];
    const int tid = threadIdx.x;
    const int lane = tid & 63, wave = tid >> 6;
    const int px = lane & 15, kl = lane >> 4;
    const int ty = blockIdx.x >> 2, tx = blockIdx.x & 3;
    const int hg = blockIdx.y, b = blockIdx.z;
    const int gy0 = ty * TR, gx0 = tx * TC;
    const int nch = (t > 0) ? 3 : 1;
    const float* hb = (t > 0) ? (hall + ((size_t)(b * T_ + t - 1)) * HID * HW) : nullptr;
    const float* xb = x + ((size_t)(b * T_ + t)) * CIN * HW;
    f32x4 accR[2] = {}, accZ[2] = {}, accNX[2] = {}, accNH[2] = {};
    float ireg[23]; bf16x8 areg[7];
    auto load_in = [&](int ch) {
        const float* src = (ch == 0) ? xb : (hb + (size_t)(ch - 1) * KCH * HW);
        #pragma unroll
        for (int j = 0; j < 23; ++j) {
            int e = tid + j * 256; float v = 0.f;
            if (e < PR * PC * KCH) {
                int ic = e / (PR * PC); int rem = e - ic * (PR * PC);
                int r = rem / PC, c = rem - r * PC;
                int gy = gy0 + r - 1, gx = gx0 + c - 1;
                if ((unsigned)gy < (unsigned)HH && (unsigned)gx < (unsigned)WW)
                    v = src[ic * HW + gy * WW + gx];
            }
            ireg[j] = v;
        }
    };
    auto load_Ar = [&](int ch) {
        const unsigned short* s = A2 + (size_t)(ch * 4 + hg) * R4_ASLAB;
        #pragma unroll
        for (int j = 0; j < 7; ++j) { int v = tid + j * 256; if (v < R4_AVEC) areg[j] = *(const bf16x8*)(s + v * 8); }
    };
    auto write_in = [&]() {
        #pragma unroll
        for (int j = 0; j < 23; ++j) {
            int e = tid + j * 256;
            if (e < PR * PC * KCH) {
                int ic = e / (PR * PC); int rem = e - ic * (PR * PC);
                int r = rem / PC, c = rem - r * PC;
                tin[(r * PC + c) * 40 + ic] = f2bf(ireg[j]);
            }
        }
    };
    auto write_Ar = [&]() {
        #pragma unroll
        for (int j = 0; j < 7; ++j) {
            int v = tid + j * 256;
            if (v < R4_AVEC) {
                int row = v / 36; int kb = (v - row * 36) * 16;
                char* dst = (char*)Alr + row * F_AROWB + (kb ^ ((row & 7) << 4));
                *(bf16x8*)dst = areg[j];
            }
        }
    };
    const int rb0 = ((wave * 2 + 0) * PC + px) * 40 + kl * 8;
    const int rb1 = rb0 + PC * 40;
    const int swA = (px & 7) << 4;
    auto compute = [&](bool isX) {
        #pragma unroll
        for (int tap = 0; tap < 9; ++tap) {
            const int dy = tap / 3, dx = tap - 3 * dy;
            const int toff = (dy * PC + dx) * 40;
            bf16x8 b0 = *(const bf16x8*)(tin + rb0 + toff);
            bf16x8 b1 = *(const bf16x8*)(tin + rb1 + toff);
            const char* ab = (const char*)Alr + px * F_AROWB + ((tap * 64 + kl * 16) ^ swA);
            bf16x8 ar = *(const bf16x8*)(ab);
            bf16x8 az = *(const bf16x8*)(ab + 16 * F_AROWB);
            bf16x8 an = *(const bf16x8*)(ab + 32 * F_AROWB);
            accR[0] = __builtin_amdgcn_mfma_f32_16x16x32_bf16(ar, b0, accR[0], 0, 0, 0);
            accR[1] = __builtin_amdgcn_mfma_f32_16x16x32_bf16(ar, b1, accR[1], 0, 0, 0);
            accZ[0] = __builtin_amdgcn_mfma_f32_16x16x32_bf16(az, b0, accZ[0], 0, 0, 0);
            accZ[1] = __builtin_amdgcn_mfma_f32_16x16x32_bf16(az, b1, accZ[1], 0, 0, 0);
            if (isX) {
                accNX[0] = __builtin_amdgcn_mfma_f32_16x16x32_bf16(an, b0, accNX[0], 0, 0, 0);
                accNX[1] = __builtin_amdgcn_mfma_f32_16x16x32_bf16(an, b1, accNX[1], 0, 0, 0);
            } else {
                accNH[0] = __builtin_amdgcn_mfma_f32_16x16x32_bf16(an, b0, accNH[0], 0, 0, 0);
                accNH[1] = __builtin_amdgcn_mfma_f32_16x16x32_bf16(an, b1, accNH[1], 0, 0, 0);
            }
        }
    };
    load_in(0); load_Ar(0); write_in(); write_Ar();
    __syncthreads();
    for (int ch = 0; ch < nch; ++ch) {
        if (ch + 1 < nch) { load_in(ch + 1); load_Ar(ch + 1); }
        compute(ch == 0);
        __syncthreads();
        if (ch + 1 < nch) { write_in(); write_Ar(); __syncthreads(); }
    }
    float* outp = out + ((size_t)(b * T_ + t)) * HID * HW;
    #pragma unroll
    for (int g = 0; g < 2; ++g) {
        int gy = gy0 + wave * 2 + g; int gx = gx0 + px;
        #pragma unroll
        for (int q = 0; q < 4; ++q) {
            int c = hg * 16 + kl * 4 + q;
            float sr = 1.f / (1.f + expf(-accR[g][q]));
            float sz = 1.f / (1.f + expf(-accZ[g][q]));
            float nn = tanhf(accNX[g][q] + sr * accNH[g][q]);
            float hv = hb ? hb[(size_t)c * HW + gy * WW + gx] : 0.f;
            outp[(size_t)c * HW + gy * WW + gx] = (1.f - sz) * nn + sz * hv;
        }
    }
}

extern "C" void kernel_launch(void* const* d_in, const int* in_sizes, int n_in,
                              void* d_out, int out_size, void* d_ws, size_t ws_size,
                              hipStream_t stream) {
    const float* x  = (const float*)d_in[0];
    const float* Wi = (const float*)d_in[1];
    const float* Wh = (const float*)d_in[2];
    float* out = (float*)d_out;

    if (ws_size >= WS_NEED_BYTES) {
        unsigned short* A2  = (unsigned short*)d_ws;
        unsigned short* xT  = A2 + XT_OFF;
        unsigned short* hT0 = A2 + HT_OFF;
        unsigned short* hT1 = hT0 + HTBUF_HW;

        wconv<<<(ATOTAL + 255) / 256, 256, 0, stream>>>(Wi, Wh, A2);
        xfill<<<dim3(66, 64), 256, 0, stream>>>(x, xT);
        {
            int n16 = (int)(2 * HTBUF_HW / 8);
            hzero<<<(n16 + 255) / 256, 256, 0, stream>>>(hT0, n16);
        }
        for (int t = 0; t < T_; ++t) {
            unsigned short* rd = (t & 1) ? hT1 : hT0;
            unsigned short* wr = (t & 1) ? hT0 : hT1;
            convgru_mfma<<<dim3(32, 4, 4), 256, 0, stream>>>(xT, A2, rd, wr, out, t);
        }
    } else {
        unsigned short* A2 = (unsigned short*)d_ws;
        wconv_r4<<<(R4_ATOT + 255) / 256, 256, 0, stream>>>(Wi, Wh, A2);
        for (int t = 0; t < T_; ++t)
            convgru_r4<<<dim3(32, 4, 4), 256, 0, stream>>>(x, A2, out, out, t);
    }
}

// Round 8
// 254.316 us; speedup vs baseline: 1.0895x; 1.0895x over previous
//
#include <hip/hip_runtime.h>
#include <math.h>

// Problem dims
constexpr int B_  = 4;
constexpr int T_  = 16;
constexpr int CIN = 32;
constexpr int HID = 64;
constexpr int HH  = 64;
constexpr int WW  = 64;
constexpr int HW  = HH * WW; // 4096

// ---------------- MFMA path config ----------------
constexpr int TR = 8,  TC = 16;         // output pixel tile: 8 rows x 16 cols
constexpr int PR = TR + 2, PC = TC + 2; // 10 x 18 (halo)
constexpr int CSL = 36;                 // channel slots per pixel (72B, 32 used)
constexpr int KCH = 32;                 // channels per K-chunk
// A slab (per chunk, per hg): [gate3][g36 = tap*4+kl][row16] 16B granules
constexpr int ASLAB_HW  = 3 * 36 * 16 * 8;            // 13824 halfwords (27648 B)
constexpr int A_GRAN    = ASLAB_HW / 8;               // 1728 granules
constexpr int ATOTAL    = 12 * ASLAB_HW;              // all slabs
constexpr int TIN_HW    = PR * PC * CSL;              // 6480 halfwords (12960 B)
constexpr int TIN_GRAN  = TIN_HW / 8;                 // 810 granules
constexpr int ROW_HW    = 66 * CSL;                   // 2376 hw per padded image row
constexpr int PIMG_HW   = 66 * ROW_HW;                // 156816 hw per padded image

// ws layout (halfword offsets)
constexpr size_t A2_HW    = (size_t)ATOTAL;
constexpr size_t XT_OFF   = A2_HW;
constexpr size_t XT_HW    = (size_t)64 * PIMG_HW;
constexpr size_t HT_OFF   = XT_OFF + XT_HW;
constexpr size_t HTBUF_HW = (size_t)8 * PIMG_HW;      // [b4][chunk2] images
constexpr size_t WS_NEED_BYTES = (A2_HW + XT_HW + 2 * HTBUF_HW) * 2;

typedef __attribute__((ext_vector_type(8))) short bf16x8;
typedef __attribute__((ext_vector_type(4))) float f32x4;

#define GLOAD_LDS16(gsrc, ldst) \
  __builtin_amdgcn_global_load_lds((const __attribute__((address_space(1))) void*)(gsrc), \
                                   (__attribute__((address_space(3))) void*)(ldst), 16, 0, 0)

__device__ inline unsigned short f2bf(float f) {
    union { float f; unsigned u; } v; v.f = f;
    return (unsigned short)((v.u + 0x7FFFu + ((v.u >> 16) & 1u)) >> 16);
}
__device__ inline float bf2f(unsigned short h) {
    union { unsigned u; float f; } v; v.u = (unsigned)h << 16; return v.f;
}

// ---- prepass 1: weights -> bf16, transposed granules [ch][hg][gate][tap*4+kl][row16] ----
__global__ void wconv(const float* __restrict__ Wi, const float* __restrict__ Wh,
                      unsigned short* __restrict__ A2) {
    int idx = blockIdx.x * 256 + threadIdx.x;
    if (idx >= ATOTAL) return;
    int ic  = idx & 31;
    int r1  = idx >> 5;
    int tap = r1 % 9;
    int r2  = r1 / 9;
    int m   = r2 & 15;
    int r3  = r2 >> 4;
    int gt  = r3 % 3;
    int r4  = r3 / 3;
    int hg  = r4 & 3;
    int ch  = r4 >> 2;
    int o   = gt * 64 + hg * 16 + m;
    float w = (ch == 0) ? Wi[(o * CIN + ic) * 9 + tap]
                        : Wh[(o * HID + (ch - 1) * 32 + ic) * 9 + tap];
    size_t dst = (size_t)(ch * 4 + hg) * ASLAB_HW
               + ((size_t)(gt * 36 + tap * 4 + (ic >> 3)) * 16 + m) * 8 + (ic & 7);
    A2[dst] = f2bf(w);
}

// ---- prepass 2: x -> channel-last padded bf16 xT[bt][66][66][36] (coalesced) ----
__global__ void xfill(const float* __restrict__ x, unsigned short* __restrict__ xT) {
    const int riT = blockIdx.x;   // 0..65
    const int bt  = blockIdx.y;   // 0..63
    unsigned short* dst = xT + (size_t)bt * PIMG_HW + (size_t)riT * ROW_HW;
    __shared__ float lds[64 * 41];

    const bool interior = (riT >= 1 && riT <= 64);
    if (interior) {
        const float* src = x + (size_t)bt * 32 * HW + (riT - 1) * WW;
        const int p = threadIdx.x & 63;
        #pragma unroll
        for (int j = 0; j < 8; ++j) {
            int c = j * 4 + (threadIdx.x >> 6);
            lds[p * 41 + c] = src[c * HW + p];   // coalesced 256B reads
        }
    }
    __syncthreads();
    for (int g = threadIdx.x; g < ROW_HW / 8; g += 256) {   // 297 granules
        bf16x8 vv;
        #pragma unroll
        for (int k = 0; k < 8; ++k) {
            int off = g * 8 + k;
            int px = off / CSL, slot = off - px * CSL;
            float v = 0.f;
            if (interior && slot < 32 && px >= 1 && px <= 64)
                v = lds[(px - 1) * 41 + slot];
            vv[k] = (short)f2bf(v);
        }
        *(bf16x8*)(dst + g * 8) = vv;                        // coalesced 16B writes
    }
}

// ---- prepass 3: zero both hT buffers (halo ring must be 0) ----
__global__ void hzero(unsigned short* __restrict__ hT, int n16) {
    int i = blockIdx.x * 256 + threadIdx.x;
    if (i < n16) ((f32x4*)hT)[i] = f32x4{0.f, 0.f, 0.f, 0.f};
}

// ---- fused ConvGRU step (MFMA; r6 barrier shape; A reg-staged; 3 tin buffers) ----
// grid (32 tiles, 4 hg, 4 b), 256 thr (4 waves; wave w owns output rows 2w,2w+1)
__global__ __launch_bounds__(256, 2) void convgru_mfma(
    const unsigned short* __restrict__ xT,   // [64][66][66][36]
    const unsigned short* __restrict__ A2,   // transposed slabs
    const unsigned short* __restrict__ hTrd, // [b][chunk][66][66][36] (t-1)
    unsigned short* __restrict__ hTwr,       // same layout (t)
    float* __restrict__ out, int t)
{
    __shared__ __align__(16) unsigned short tA[TIN_HW];   // 12960 B (x, then h_hi)
    __shared__ __align__(16) unsigned short tB[TIN_HW];   // h_lo
    __shared__ __align__(16) unsigned short tC[TIN_HW];   // h_hi
    __shared__ __align__(16) unsigned short Al[ASLAB_HW]; // 27648 B

    const int tid  = threadIdx.x;
    const int lane = tid & 63, wave = tid >> 6;
    const int px   = lane & 15, kl = lane >> 4;  // px = A row = B col = C col
    const int ty = blockIdx.x >> 2, tx = blockIdx.x & 3;
    const int hg = blockIdx.y, b = blockIdx.z;
    const int gy0 = ty * TR, gx0 = tx * TC;

    const unsigned short* xs = xT + (size_t)(b * T_ + t) * PIMG_HW;

    f32x4 accR[2] = {}, accZ[2] = {}, accNX[2] = {}, accNH[2] = {};
    bf16x8 areg[7];

    const int rowbase = gy0 * 66 + gx0;   // halo-origin pixel index in padded image

    auto stage_tin = [&](const unsigned short* src, unsigned short* dst) {
        #pragma unroll
        for (int j = 0; j < 4; ++j) {
            int G = tid + j * 256;
            if (G < TIN_GRAN) {
                int r = G / 81, w = G - 81 * r;   // 81 granules per halo row
                GLOAD_LDS16(src + (size_t)(rowbase + r * 66) * CSL + w * 8, dst + G * 8);
            }
        }
    };
    auto dma_A = [&](int ch) {
        const unsigned short* s = A2 + (size_t)(ch * 4 + hg) * ASLAB_HW;
        #pragma unroll
        for (int j = 0; j < 7; ++j) {
            int v = tid + j * 256;
            if (v < A_GRAN) GLOAD_LDS16(s + v * 8, Al + v * 8);
        }
    };
    auto reg_A = [&](int ch) {
        const unsigned short* s = A2 + (size_t)(ch * 4 + hg) * ASLAB_HW;
        #pragma unroll
        for (int j = 0; j < 7; ++j) {
            int v = tid + j * 256;
            if (v < A_GRAN) areg[j] = *(const bf16x8*)(s + v * 8);
        }
    };
    auto wr_A = [&]() {
        #pragma unroll
        for (int j = 0; j < 7; ++j) {
            int v = tid + j * 256;
            if (v < A_GRAN) *(bf16x8*)(Al + v * 8) = areg[j];
        }
    };

    // B-frag read bases (halfword): pixel (r,c) at (r*18+c)*36
    const int rb0 = ((wave * 2 + 0) * PC + px) * CSL + kl * 8;
    const int rb1 = rb0 + PC * CSL;
    const int aoff = (kl * 16 + px) * 8;   // lane's granule offset in a gate/tap block

    auto compute = [&](const unsigned short* tb, bool isX) {
        const unsigned short* ab = Al + aoff;
        #pragma unroll
        for (int tap = 0; tap < 9; ++tap) {
            const int dy = tap / 3, dx = tap - 3 * dy;
            const int toff = (dy * PC + dx) * CSL;
            bf16x8 b0 = *(const bf16x8*)(tb + rb0 + toff);
            bf16x8 b1 = *(const bf16x8*)(tb + rb1 + toff);
            bf16x8 ar = *(const bf16x8*)(ab + tap * 512);
            bf16x8 az = *(const bf16x8*)(ab + tap * 512 + 4608);
            bf16x8 an = *(const bf16x8*)(ab + tap * 512 + 9216);
            accR[0] = __builtin_amdgcn_mfma_f32_16x16x32_bf16(ar, b0, accR[0], 0, 0, 0);
            accR[1] = __builtin_amdgcn_mfma_f32_16x16x32_bf16(ar, b1, accR[1], 0, 0, 0);
            accZ[0] = __builtin_amdgcn_mfma_f32_16x16x32_bf16(az, b0, accZ[0], 0, 0, 0);
            accZ[1] = __builtin_amdgcn_mfma_f32_16x16x32_bf16(az, b1, accZ[1], 0, 0, 0);
            if (isX) {
                accNX[0] = __builtin_amdgcn_mfma_f32_16x16x32_bf16(an, b0, accNX[0], 0, 0, 0);
                accNX[1] = __builtin_amdgcn_mfma_f32_16x16x32_bf16(an, b1, accNX[1], 0, 0, 0);
            } else {
                accNH[0] = __builtin_amdgcn_mfma_f32_16x16x32_bf16(an, b0, accNH[0], 0, 0, 0);
                accNH[1] = __builtin_amdgcn_mfma_f32_16x16x32_bf16(an, b1, accNH[1], 0, 0, 0);
            }
        }
    };

    // ---- schedule ----
    stage_tin(xs, tA);
    dma_A(0);
    if (t > 0) reg_A(1);                 // global->VGPR, hides under chunk0 staging
    __syncthreads();                     // tA + Al(0) ready
    if (t > 0) {
        const unsigned short* h0 = hTrd + (size_t)(b * 2 + 0) * PIMG_HW;
        const unsigned short* h1 = hTrd + (size_t)(b * 2 + 1) * PIMG_HW;
        stage_tin(h0, tB);               // DMA prefetch h_lo
        stage_tin(h1, tC);               // DMA prefetch h_hi
    }
    compute(tA, true);
    if (t > 0) {
        __syncthreads();                 // tB/tC ready (drained; overlapped compute0)
        wr_A();                          // Al <- A(1)
        reg_A(2);                        // prefetch A(2) to regs (hides under compute1)
        __syncthreads();                 // Al(1) visible
        compute(tB, false);
        __syncthreads();                 // compute1 done (Al free)
        wr_A();                          // Al <- A(2)
        __syncthreads();                 // Al(2) visible
        compute(tC, false);
    }

    // ---- epilogue: gates + state update; h_prev (bf16) from retained LDS ----
    float* outp = out + ((size_t)(b * T_ + t)) * HID * HW;
    const int c0   = hg * 16 + kl * 4;
    const int slot = c0 & 31;
    const unsigned short* hbuf = (hg < 2) ? tB : tC;
    #pragma unroll
    for (int g = 0; g < 2; ++g) {
        int gy = gy0 + wave * 2 + g;
        int gx = gx0 + px;
        float hvf[4] = {0.f, 0.f, 0.f, 0.f};
        if (t > 0) {
            const unsigned short* hp =
                hbuf + ((wave * 2 + g + 1) * PC + (px + 1)) * CSL + slot;
            #pragma unroll
            for (int q = 0; q < 4; ++q) hvf[q] = bf2f(hp[q]);
        }
        unsigned short hvals[4];
        #pragma unroll
        for (int q = 0; q < 4; ++q) {
            int c = c0 + q;
            float sr = __builtin_amdgcn_rcpf(1.f + __expf(-accR[g][q]));
            float sz = __builtin_amdgcn_rcpf(1.f + __expf(-accZ[g][q]));
            float ag = accNX[g][q] + sr * accNH[g][q];
            float nn = 2.f * __builtin_amdgcn_rcpf(1.f + __expf(-2.f * ag)) - 1.f;
            float hn = nn + sz * (hvf[q] - nn);
            outp[(size_t)c * HW + gy * WW + gx] = hn;
            hvals[q] = f2bf(hn);
        }
        unsigned short* hd = hTwr + (size_t)(b * 2 + (c0 >> 5)) * PIMG_HW
                           + (size_t)((gy + 1) * 66 + (gx + 1)) * CSL + slot;
        *(uint2*)hd = *(const uint2*)hvals;
    }
}

// ================= round-4 fallback (known-pass, tiny ws) =================
constexpr int F_AROWB = 640;
constexpr int R4_ASLAB = 48 * 9 * KCH;
constexpr int R4_AVEC  = R4_ASLAB / 8;
constexpr int R4_ATOT  = 12 * R4_ASLAB;
__global__ void wconv_r4(const float* __restrict__ Wi, const float* __restrict__ Wh,
                         unsigned short* __restrict__ A2) {
    int idx = blockIdx.x * 256 + threadIdx.x;
    if (idx >= R4_ATOT) return;
    int ic = idx & 31; int r1 = idx >> 5;
    int tap = r1 % 9; int r2 = r1 / 9;
    int m = r2 & 15; int r3 = r2 >> 4;
    int gt = r3 % 3; int r4 = r3 / 3;
    int hg = r4 & 3; int ch = r4 >> 2;
    int o = gt * 64 + hg * 16 + m;
    float w = (ch == 0) ? Wi[(o * CIN + ic) * 9 + tap]
                        : Wh[(o * HID + (ch - 1) * 32 + ic) * 9 + tap];
    A2[idx] = f2bf(w);
}
__global__ __launch_bounds__(256, 2) void convgru_r4(
    const float* __restrict__ x, const unsigned short* __restrict__ A2,
    const float* hall, float* out, int t)
{
    __shared__ __align__(16) unsigned short tin[PR * PC * 40];
    __shared__ __align__(16) unsigned short Alr[48 * (F_AROWB / 2)];
    const int tid = threadIdx.x;
    const int lane = tid & 63, wave = tid >> 6;
    const int px = lane & 15, kl = lane >> 4;
    const int ty = blockIdx.x >> 2, tx = blockIdx.x & 3;
    const int hg = blockIdx.y, b = blockIdx.z;
    const int gy0 = ty * TR, gx0 = tx * TC;
    const int nch = (t > 0) ? 3 : 1;
    const float* hb = (t > 0) ? (hall + ((size_t)(b * T_ + t - 1)) * HID * HW) : nullptr;
    const float* xb = x + ((size_t)(b * T_ + t)) * CIN * HW;
    f32x4 accR[2] = {}, accZ[2] = {}, accNX[2] = {}, accNH[2] = {};
    float ireg[23]; bf16x8 areg[7];
    auto load_in = [&](int ch) {
        const float* src = (ch == 0) ? xb : (hb + (size_t)(ch - 1) * KCH * HW);
        #pragma unroll
        for (int j = 0; j < 23; ++j) {
            int e = tid + j * 256; float v = 0.f;
            if (e < PR * PC * KCH) {
                int ic = e / (PR * PC); int rem = e - ic * (PR * PC);
                int r = rem / PC, c = rem - r * PC;
                int gy = gy0 + r - 1, gx = gx0 + c - 1;
                if ((unsigned)gy < (unsigned)HH && (unsigned)gx < (unsigned)WW)
                    v = src[ic * HW + gy * WW + gx];
            }
            ireg[j] = v;
        }
    };
    auto load_Ar = [&](int ch) {
        const unsigned short* s = A2 + (size_t)(ch * 4 + hg) * R4_ASLAB;
        #pragma unroll
        for (int j = 0; j < 7; ++j) { int v = tid + j * 256; if (v < R4_AVEC) areg[j] = *(const bf16x8*)(s + v * 8); }
    };
    auto write_in = [&]() {
        #pragma unroll
        for (int j = 0; j < 23; ++j) {
            int e = tid + j * 256;
            if (e < PR * PC * KCH) {
                int ic = e / (PR * PC); int rem = e - ic * (PR * PC);
                int r = rem / PC, c = rem - r * PC;
                tin[(r * PC + c) * 40 + ic] = f2bf(ireg[j]);
            }
        }
    };
    auto write_Ar = [&]() {
        #pragma unroll
        for (int j = 0; j < 7; ++j) {
            int v = tid + j * 256;
            if (v < R4_AVEC) {
                int row = v / 36; int kb = (v - row * 36) * 16;
                char* dst = (char*)Alr + row * F_AROWB + (kb ^ ((row & 7) << 4));
                *(bf16x8*)dst = areg[j];
            }
        }
    };
    const int rb0 = ((wave * 2 + 0) * PC + px) * 40 + kl * 8;
    const int rb1 = rb0 + PC * 40;
    const int swA = (px & 7) << 4;
    auto compute = [&](bool isX) {
        #pragma unroll
        for (int tap = 0; tap < 9; ++tap) {
            const int dy = tap / 3, dx = tap - 3 * dy;
            const int toff = (dy * PC + dx) * 40;
            bf16x8 b0 = *(const bf16x8*)(tin + rb0 + toff);
            bf16x8 b1 = *(const bf16x8*)(tin + rb1 + toff);
            const char* ab = (const char*)Alr + px * F_AROWB + ((tap * 64 + kl * 16) ^ swA);
            bf16x8 ar = *(const bf16x8*)(ab);
            bf16x8 az = *(const bf16x8*)(ab + 16 * F_AROWB);
            bf16x8 an = *(const bf16x8*)(ab + 32 * F_AROWB);
            accR[0] = __builtin_amdgcn_mfma_f32_16x16x32_bf16(ar, b0, accR[0], 0, 0, 0);
            accR[1] = __builtin_amdgcn_mfma_f32_16x16x32_bf16(ar, b1, accR[1], 0, 0, 0);
            accZ[0] = __builtin_amdgcn_mfma_f32_16x16x32_bf16(az, b0, accZ[0], 0, 0, 0);
            accZ[1] = __builtin_amdgcn_mfma_f32_16x16x32_bf16(az, b1, accZ[1], 0, 0, 0);
            if (isX) {
                accNX[0] = __builtin_amdgcn_mfma_f32_16x16x32_bf16(an, b0, accNX[0], 0, 0, 0);
                accNX[1] = __builtin_amdgcn_mfma_f32_16x16x32_bf16(an, b1, accNX[1], 0, 0, 0);
            } else {
                accNH[0] = __builtin_amdgcn_mfma_f32_16x16x32_bf16(an, b0, accNH[0], 0, 0, 0);
                accNH[1] = __builtin_amdgcn_mfma_f32_16x16x32_bf16(an, b1, accNH[1], 0, 0, 0);
            }
        }
    };
    load_in(0); load_Ar(0); write_in(); write_Ar();
    __syncthreads();
    for (int ch = 0; ch < nch; ++ch) {
        if (ch + 1 < nch) { load_in(ch + 1); load_Ar(ch + 1); }
        compute(ch == 0);
        __syncthreads();
        if (ch + 1 < nch) { write_in(); write_Ar(); __syncthreads(); }
    }
    float* outp = out + ((size_t)(b * T_ + t)) * HID * HW;
    #pragma unroll
    for (int g = 0; g < 2; ++g) {
        int gy = gy0 + wave * 2 + g; int gx = gx0 + px;
        #pragma unroll
        for (int q = 0; q < 4; ++q) {
            int c = hg * 16 + kl * 4 + q;
            float sr = 1.f / (1.f + expf(-accR[g][q]));
            float sz = 1.f / (1.f + expf(-accZ[g][q]));
            float nn = tanhf(accNX[g][q] + sr * accNH[g][q]);
            float hv = hb ? hb[(size_t)c * HW + gy * WW + gx] : 0.f;
            outp[(size_t)c * HW + gy * WW + gx] = (1.f - sz) * nn + sz * hv;
        }
    }
}

extern "C" void kernel_launch(void* const* d_in, const int* in_sizes, int n_in,
                              void* d_out, int out_size, void* d_ws, size_t ws_size,
                              hipStream_t stream) {
    const float* x  = (const float*)d_in[0];
    const float* Wi = (const float*)d_in[1];
    const float* Wh = (const float*)d_in[2];
    float* out = (float*)d_out;

    if (ws_size >= WS_NEED_BYTES) {
        unsigned short* A2  = (unsigned short*)d_ws;
        unsigned short* xT  = A2 + XT_OFF;
        unsigned short* hT0 = A2 + HT_OFF;
        unsigned short* hT1 = hT0 + HTBUF_HW;

        wconv<<<(ATOTAL + 255) / 256, 256, 0, stream>>>(Wi, Wh, A2);
        xfill<<<dim3(66, 64), 256, 0, stream>>>(x, xT);
        {
            int n16 = (int)(2 * HTBUF_HW / 8);
            hzero<<<(n16 + 255) / 256, 256, 0, stream>>>(hT0, n16);
        }
        for (int t = 0; t < T_; ++t) {
            unsigned short* rd = (t & 1) ? hT1 : hT0;
            unsigned short* wr = (t & 1) ? hT0 : hT1;
            convgru_mfma<<<dim3(32, 4, 4), 256, 0, stream>>>(xT, A2, rd, wr, out, t);
        }
    } else {
        unsigned short* A2 = (unsigned short*)d_ws;
        wconv_r4<<<(R4_ATOT + 255) / 256, 256, 0, stream>>>(Wi, Wh, A2);
        for (int t = 0; t < T_; ++t)
            convgru_r4<<<dim3(32, 4, 4), 256, 0, stream>>>(x, A2, out, out, t);
    }
}

// Round 9
// 174.514 us; speedup vs baseline: 1.5878x; 1.4573x over previous
//
#include <hip/hip_runtime.h>
#include <math.h>

// Problem dims
constexpr int B_  = 4;
constexpr int T_  = 16;
constexpr int CIN = 32;
constexpr int HID = 64;
constexpr int HH  = 64;
constexpr int WW  = 64;
constexpr int HW  = HH * WW; // 4096

// ---------------- MFMA path config ----------------
constexpr int TR = 8,  TC = 16;         // output pixel tile: 8 rows x 16 cols
constexpr int PR = TR + 2, PC = TC + 2; // 10 x 18 (halo)
constexpr int CSL = 40;                 // channel slots per pixel (80B; free 2-way banks)
constexpr int KCH = 32;                 // channels per K-chunk
// A slab (per chunk, per hg): [gate3][tap9*4+klgrp][row16] 16B granules
constexpr int ASLAB_HW  = 3 * 36 * 16 * 8;            // 13824 halfwords (27648 B)
constexpr int ATOTAL    = 12 * ASLAB_HW;              // 165888 weight elements
constexpr int TIN_HW    = PR * PC * CSL;              // 7200 halfwords (14400 B)
constexpr int TIN_GRAN  = TIN_HW / 8;                 // 900 granules
constexpr int ROW_HW    = 66 * CSL;                   // 2640 hw per padded image row
constexpr int PIMG_HW   = 66 * ROW_HW;                // 174240 hw per padded image

// ws layout (halfword offsets)
constexpr size_t A2_HW    = (size_t)ATOTAL;
constexpr size_t XT_OFF   = A2_HW;
constexpr size_t XT_HW    = (size_t)64 * PIMG_HW;
constexpr size_t HT_OFF   = XT_OFF + XT_HW;
constexpr size_t HTBUF_HW = (size_t)8 * PIMG_HW;      // [b4][chunk2] images
constexpr size_t WS_NEED_BYTES = (A2_HW + XT_HW + 2 * HTBUF_HW) * 2;

typedef __attribute__((ext_vector_type(8))) short bf16x8;
typedef __attribute__((ext_vector_type(4))) float f32x4;

#define GLOAD_LDS16(gsrc, ldst) \
  __builtin_amdgcn_global_load_lds((const __attribute__((address_space(1))) void*)(gsrc), \
                                   (__attribute__((address_space(3))) void*)(ldst), 16, 0, 0)

__device__ inline unsigned short f2bf(float f) {
    union { float f; unsigned u; } v; v.f = f;
    return (unsigned short)((v.u + 0x7FFFu + ((v.u >> 16) & 1u)) >> 16);
}
__device__ inline float bf2f(unsigned short h) {
    union { unsigned u; float f; } v; v.u = (unsigned)h << 16; return v.f;
}

// ---- prepass 1: weights -> bf16, transposed granules [ch][hg][gate][tap*4+klgrp][row16] ----
__global__ void wconv(const float* __restrict__ Wi, const float* __restrict__ Wh,
                      unsigned short* __restrict__ A2) {
    int idx = blockIdx.x * 256 + threadIdx.x;
    if (idx >= ATOTAL) return;
    int ic  = idx & 31;
    int r1  = idx >> 5;
    int tap = r1 % 9;
    int r2  = r1 / 9;
    int m   = r2 & 15;
    int r3  = r2 >> 4;
    int gt  = r3 % 3;
    int r4  = r3 / 3;
    int hg  = r4 & 3;
    int ch  = r4 >> 2;
    int o   = gt * 64 + hg * 16 + m;
    float w = (ch == 0) ? Wi[(o * CIN + ic) * 9 + tap]
                        : Wh[(o * HID + (ch - 1) * 32 + ic) * 9 + tap];
    size_t dst = (size_t)(ch * 4 + hg) * ASLAB_HW
               + ((size_t)(gt * 36 + tap * 4 + (ic >> 3)) * 16 + m) * 8 + (ic & 7);
    A2[dst] = f2bf(w);
}

// ---- prepass 2: x -> channel-last padded bf16 xT[bt][66][66][40] (coalesced) ----
__global__ void xfill(const float* __restrict__ x, unsigned short* __restrict__ xT) {
    const int riT = blockIdx.x;   // 0..65
    const int bt  = blockIdx.y;   // 0..63
    unsigned short* dst = xT + (size_t)bt * PIMG_HW + (size_t)riT * ROW_HW;
    __shared__ float lds[64 * 41];

    const bool interior = (riT >= 1 && riT <= 64);
    if (interior) {
        const float* src = x + (size_t)bt * 32 * HW + (riT - 1) * WW;
        const int p = threadIdx.x & 63;
        #pragma unroll
        for (int j = 0; j < 8; ++j) {
            int c = j * 4 + (threadIdx.x >> 6);
            lds[p * 41 + c] = src[c * HW + p];   // coalesced 256B reads
        }
    }
    __syncthreads();
    for (int g = threadIdx.x; g < ROW_HW / 8; g += 256) {   // 330 granules
        bf16x8 vv;
        #pragma unroll
        for (int k = 0; k < 8; ++k) {
            int off = g * 8 + k;
            int px = off / CSL, slot = off - px * CSL;
            float v = 0.f;
            if (interior && slot < 32 && px >= 1 && px <= 64)
                v = lds[(px - 1) * 41 + slot];
            vv[k] = (short)f2bf(v);
        }
        *(bf16x8*)(dst + g * 8) = vv;                        // coalesced 16B writes
    }
}

// ---- prepass 3: zero both hT buffers (halo ring must be 0) ----
__global__ void hzero(unsigned short* __restrict__ hT, int n16) {
    int i = blockIdx.x * 256 + threadIdx.x;
    if (i < n16) ((f32x4*)hT)[i] = f32x4{0.f, 0.f, 0.f, 0.f};
}

// ---- fused ConvGRU step: A in VGPRs, dedup B-reads, 1 barrier, DMA tin staging ----
// grid (32 tiles, 4 hg, 4 b), 256 thr (4 waves; wave w owns output rows 2w,2w+1)
__global__ __launch_bounds__(256, 2) void convgru_mfma(
    const unsigned short* __restrict__ xT,   // [64][66][66][40]
    const unsigned short* __restrict__ A2,   // transposed slabs
    const unsigned short* __restrict__ hTrd, // [b][chunk][66][66][40] (t-1)
    unsigned short* __restrict__ hTwr,       // same layout (t)
    float* __restrict__ out, int t)
{
    __shared__ __align__(16) unsigned short t0s[TIN_HW];  // x tile
    __shared__ __align__(16) unsigned short t1s[TIN_HW];  // h ch 0-31
    __shared__ __align__(16) unsigned short t2s[TIN_HW];  // h ch 32-63

    const int tid  = threadIdx.x;
    const int lane = tid & 63, wave = tid >> 6;
    const int px   = lane & 15, kl = lane >> 4;  // px = A row = B col = C col
    const int ty = blockIdx.x >> 2, tx = blockIdx.x & 3;
    const int hg = blockIdx.y, b = blockIdx.z;
    const int gy0 = ty * TR, gx0 = tx * TC;

    const unsigned short* xs = xT + (size_t)(b * T_ + t) * PIMG_HW;
    const int rowbase = gy0 * 66 + gx0;   // halo-origin pixel index in padded image

    f32x4 accR[2] = {}, accZ[2] = {}, accNX[2] = {}, accNH[2] = {};
    bf16x8 a[27];                         // current chunk's A fragments (statically indexed)

    auto stage_tin = [&](const unsigned short* src, unsigned short* dst) {
        #pragma unroll
        for (int j = 0; j < 4; ++j) {
            int G = tid + j * 256;
            if (G < TIN_GRAN) {
                int r = G / 90, w = G - 90 * r;   // 90 granules per halo row
                GLOAD_LDS16(src + (size_t)(rowbase + r * 66) * CSL + w * 8, dst + G * 8);
            }
        }
    };
    auto regA = [&](int ch) {
        // lane l reads granule base+l of each (gate,tap) block: fully coalesced 1KB/wave
        const unsigned short* s = A2 + (size_t)(ch * 4 + hg) * ASLAB_HW + lane * 8;
        #pragma unroll
        for (int i = 0; i < 27; ++i)
            a[i] = *(const bf16x8*)(s + (size_t)((i / 9) * 36 + (i % 9) * 4) * 128);
    };

    // B-read base: padded row 2w, col px, k-slice kl
    const int rb = (wave * 2 * PC + px) * CSL + kl * 8;

    auto compute = [&](const unsigned short* tb, bool isX) {
        bf16x8 P[4][3];   // rows 2w..2w+3 x col shifts 0..2 (12 reads, dedup of 18)
        #pragma unroll
        for (int r = 0; r < 4; ++r)
            #pragma unroll
            for (int s = 0; s < 3; ++s)
                P[r][s] = *(const bf16x8*)(tb + rb + (r * PC + s) * CSL);
        #pragma unroll
        for (int dy = 0; dy < 3; ++dy) {
            #pragma unroll
            for (int dx = 0; dx < 3; ++dx) {
                const int tap = dy * 3 + dx;
                bf16x8 b0 = P[dy][dx], b1 = P[dy + 1][dx];
                bf16x8 ar = a[tap], az = a[9 + tap], an = a[18 + tap];
                accR[0] = __builtin_amdgcn_mfma_f32_16x16x32_bf16(ar, b0, accR[0], 0, 0, 0);
                accR[1] = __builtin_amdgcn_mfma_f32_16x16x32_bf16(ar, b1, accR[1], 0, 0, 0);
                accZ[0] = __builtin_amdgcn_mfma_f32_16x16x32_bf16(az, b0, accZ[0], 0, 0, 0);
                accZ[1] = __builtin_amdgcn_mfma_f32_16x16x32_bf16(az, b1, accZ[1], 0, 0, 0);
                if (isX) {
                    accNX[0] = __builtin_amdgcn_mfma_f32_16x16x32_bf16(an, b0, accNX[0], 0, 0, 0);
                    accNX[1] = __builtin_amdgcn_mfma_f32_16x16x32_bf16(an, b1, accNX[1], 0, 0, 0);
                } else {
                    accNH[0] = __builtin_amdgcn_mfma_f32_16x16x32_bf16(an, b0, accNH[0], 0, 0, 0);
                    accNH[1] = __builtin_amdgcn_mfma_f32_16x16x32_bf16(an, b1, accNH[1], 0, 0, 0);
                }
            }
        }
    };

    // ---- schedule: all DMA staging up front, ONE barrier ----
    stage_tin(xs, t0s);
    if (t > 0) {
        stage_tin(hTrd + (size_t)(b * 2 + 0) * PIMG_HW, t1s);
        stage_tin(hTrd + (size_t)(b * 2 + 1) * PIMG_HW, t2s);
    }
    regA(0);
    __syncthreads();                      // drains vmcnt: all tin + A(0) ready
    compute(t0s, true);
    if (t > 0) {
        regA(1);
        compute(t1s, false);
        regA(2);
        compute(t2s, false);
    }

    // ---- epilogue: gates + state update; h_prev (bf16) from retained LDS ----
    float* outp = out + ((size_t)(b * T_ + t)) * HID * HW;
    const int c0   = hg * 16 + kl * 4;
    const int slot = c0 & 31;
    const unsigned short* hbuf = (hg < 2) ? t1s : t2s;
    #pragma unroll
    for (int g = 0; g < 2; ++g) {
        int gy = gy0 + wave * 2 + g;
        int gx = gx0 + px;
        float hvf[4] = {0.f, 0.f, 0.f, 0.f};
        if (t > 0) {
            const unsigned short* hp =
                hbuf + ((wave * 2 + g + 1) * PC + (px + 1)) * CSL + slot;
            #pragma unroll
            for (int q = 0; q < 4; ++q) hvf[q] = bf2f(hp[q]);
        }
        unsigned short hvals[4];
        #pragma unroll
        for (int q = 0; q < 4; ++q) {
            int c = c0 + q;
            float sr = __builtin_amdgcn_rcpf(1.f + __expf(-accR[g][q]));
            float sz = __builtin_amdgcn_rcpf(1.f + __expf(-accZ[g][q]));
            float ag = accNX[g][q] + sr * accNH[g][q];
            float nn = 2.f * __builtin_amdgcn_rcpf(1.f + __expf(-2.f * ag)) - 1.f;
            float hn = nn + sz * (hvf[q] - nn);
            outp[(size_t)c * HW + gy * WW + gx] = hn;
            hvals[q] = f2bf(hn);
        }
        unsigned short* hd = hTwr + (size_t)(b * 2 + (c0 >> 5)) * PIMG_HW
                           + (size_t)((gy + 1) * 66 + (gx + 1)) * CSL + slot;
        *(uint2*)hd = *(const uint2*)hvals;
    }
}

// ================= round-4 fallback (known-pass, tiny ws) =================
constexpr int F_AROWB = 640;
constexpr int R4_ASLAB = 48 * 9 * KCH;
constexpr int R4_AVEC  = R4_ASLAB / 8;
constexpr int R4_ATOT  = 12 * R4_ASLAB;
__global__ void wconv_r4(const float* __restrict__ Wi, const float* __restrict__ Wh,
                         unsigned short* __restrict__ A2) {
    int idx = blockIdx.x * 256 + threadIdx.x;
    if (idx >= R4_ATOT) return;
    int ic = idx & 31; int r1 = idx >> 5;
    int tap = r1 % 9; int r2 = r1 / 9;
    int m = r2 & 15; int r3 = r2 >> 4;
    int gt = r3 % 3; int r4 = r3 / 3;
    int hg = r4 & 3; int ch = r4 >> 2;
    int o = gt * 64 + hg * 16 + m;
    float w = (ch == 0) ? Wi[(o * CIN + ic) * 9 + tap]
                        : Wh[(o * HID + (ch - 1) * 32 + ic) * 9 + tap];
    A2[idx] = f2bf(w);
}
__global__ __launch_bounds__(256, 2) void convgru_r4(
    const float* __restrict__ x, const unsigned short* __restrict__ A2,
    const float* hall, float* out, int t)
{
    __shared__ __align__(16) unsigned short tin[PR * PC * 40];
    __shared__ __align__(16) unsigned short Alr[48 * (F_AROWB / 2)];
    const int tid = threadIdx.x;
    const int lane = tid & 63, wave = tid >> 6;
    const int px = lane & 15, kl = lane >> 4;
    const int ty = blockIdx.x >> 2, tx = blockIdx.x & 3;
    const int hg = blockIdx.y, b = blockIdx.z;
    const int gy0 = ty * TR, gx0 = tx * TC;
    const int nch = (t > 0) ? 3 : 1;
    const float* hb = (t > 0) ? (hall + ((size_t)(b * T_ + t - 1)) * HID * HW) : nullptr;
    const float* xb = x + ((size_t)(b * T_ + t)) * CIN * HW;
    f32x4 accR[2] = {}, accZ[2] = {}, accNX[2] = {}, accNH[2] = {};
    float ireg[23]; bf16x8 areg[7];
    auto load_in = [&](int ch) {
        const float* src = (ch == 0) ? xb : (hb + (size_t)(ch - 1) * KCH * HW);
        #pragma unroll
        for (int j = 0; j < 23; ++j) {
            int e = tid + j * 256; float v = 0.f;
            if (e < PR * PC * KCH) {
                int ic = e / (PR * PC); int rem = e - ic * (PR * PC);
                int r = rem / PC, c = rem - r * PC;
                int gy = gy0 + r - 1, gx = gx0 + c - 1;
                if ((unsigned)gy < (unsigned)HH && (unsigned)gx < (unsigned)WW)
                    v = src[ic * HW + gy * WW + gx];
            }
            ireg[j] = v;
        }
    };
    auto load_Ar = [&](int ch) {
        const unsigned short* s = A2 + (size_t)(ch * 4 + hg) * R4_ASLAB;
        #pragma unroll
        for (int j = 0; j < 7; ++j) { int v = tid + j * 256; if (v < R4_AVEC) areg[j] = *(const bf16x8*)(s + v * 8); }
    };
    auto write_in = [&]() {
        #pragma unroll
        for (int j = 0; j < 23; ++j) {
            int e = tid + j * 256;
            if (e < PR * PC * KCH) {
                int ic = e / (PR * PC); int rem = e - ic * (PR * PC);
                int r = rem / PC, c = rem - r * PC;
                tin[(r * PC + c) * 40 + ic] = f2bf(ireg[j]);
            }
        }
    };
    auto write_Ar = [&]() {
        #pragma unroll
        for (int j = 0; j < 7; ++j) {
            int v = tid + j * 256;
            if (v < R4_AVEC) {
                int row = v / 36; int kb = (v - row * 36) * 16;
                char* dst = (char*)Alr + row * F_AROWB + (kb ^ ((row & 7) << 4));
                *(bf16x8*)dst = areg[j];
            }
        }
    };
    const int rb0 = ((wave * 2 + 0) * PC + px) * 40 + kl * 8;
    const int rb1 = rb0 + PC * 40;
    const int swA = (px & 7) << 4;
    auto compute = [&](bool isX) {
        #pragma unroll
        for (int tap = 0; tap < 9; ++tap) {
            const int dy = tap / 3, dx = tap - 3 * dy;
            const int toff = (dy * PC + dx) * 40;
            bf16x8 b0 = *(const bf16x8*)(tin + rb0 + toff);
            bf16x8 b1 = *(const bf16x8*)(tin + rb1 + toff);
            const char* ab = (const char*)Alr + px * F_AROWB + ((tap * 64 + kl * 16) ^ swA);
            bf16x8 ar = *(const bf16x8*)(ab);
            bf16x8 az = *(const bf16x8*)(ab + 16 * F_AROWB);
            bf16x8 an = *(const bf16x8*)(ab + 32 * F_AROWB);
            accR[0] = __builtin_amdgcn_mfma_f32_16x16x32_bf16(ar, b0, accR[0], 0, 0, 0);
            accR[1] = __builtin_amdgcn_mfma_f32_16x16x32_bf16(ar, b1, accR[1], 0, 0, 0);
            accZ[0] = __builtin_amdgcn_mfma_f32_16x16x32_bf16(az, b0, accZ[0], 0, 0, 0);
            accZ[1] = __builtin_amdgcn_mfma_f32_16x16x32_bf16(az, b1, accZ[1], 0, 0, 0);
            if (isX) {
                accNX[0] = __builtin_amdgcn_mfma_f32_16x16x32_bf16(an, b0, accNX[0], 0, 0, 0);
                accNX[1] = __builtin_amdgcn_mfma_f32_16x16x32_bf16(an, b1, accNX[1], 0, 0, 0);
            } else {
                accNH[0] = __builtin_amdgcn_mfma_f32_16x16x32_bf16(an, b0, accNH[0], 0, 0, 0);
                accNH[1] = __builtin_amdgcn_mfma_f32_16x16x32_bf16(an, b1, accNH[1], 0, 0, 0);
            }
        }
    };
    load_in(0); load_Ar(0); write_in(); write_Ar();
    __syncthreads();
    for (int ch = 0; ch < nch; ++ch) {
        if (ch + 1 < nch) { load_in(ch + 1); load_Ar(ch + 1); }
        compute(ch == 0);
        __syncthreads();
        if (ch + 1 < nch) { write_in(); write_Ar(); __syncthreads(); }
    }
    float* outp = out + ((size_t)(b * T_ + t)) * HID * HW;
    #pragma unroll
    for (int g = 0; g < 2; ++g) {
        int gy = gy0 + wave * 2 + g; int gx = gx0 + px;
        #pragma unroll
        for (int q = 0; q < 4; ++q) {
            int c = hg * 16 + kl * 4 + q;
            float sr = 1.f / (1.f + expf(-accR[g][q]));
            float sz = 1.f / (1.f + expf(-accZ[g][q]));
            float nn = tanhf(accNX[g][q] + sr * accNH[g][q]);
            float hv = hb ? hb[(size_t)c * HW + gy * WW + gx] : 0.f;
            outp[(size_t)c * HW + gy * WW + gx] = (1.f - sz) * nn + sz * hv;
        }
    }
}

extern "C" void kernel_launch(void* const* d_in, const int* in_sizes, int n_in,
                              void* d_out, int out_size, void* d_ws, size_t ws_size,
                              hipStream_t stream) {
    const float* x  = (const float*)d_in[0];
    const float* Wi = (const float*)d_in[1];
    const float* Wh = (const float*)d_in[2];
    float* out = (float*)d_out;

    if (ws_size >= WS_NEED_BYTES) {
        unsigned short* A2  = (unsigned short*)d_ws;
        unsigned short* xT  = A2 + XT_OFF;
        unsigned short* hT0 = A2 + HT_OFF;
        unsigned short* hT1 = hT0 + HTBUF_HW;

        wconv<<<(ATOTAL + 255) / 256, 256, 0, stream>>>(Wi, Wh, A2);
        xfill<<<dim3(66, 64), 256, 0, stream>>>(x, xT);
        {
            int n16 = (int)(2 * HTBUF_HW / 8);
            hzero<<<(n16 + 255) / 256, 256, 0, stream>>>(hT0, n16);
        }
        for (int t = 0; t < T_; ++t) {
            unsigned short* rd = (t & 1) ? hT1 : hT0;
            unsigned short* wr = (t & 1) ? hT0 : hT1;
            convgru_mfma<<<dim3(32, 4, 4), 256, 0, stream>>>(xT, A2, rd, wr, out, t);
        }
    } else {
        unsigned short* A2 = (unsigned short*)d_ws;
        wconv_r4<<<(R4_ATOT + 255) / 256, 256, 0, stream>>>(Wi, Wh, A2);
        for (int t = 0; t < T_; ++t)
            convgru_r4<<<dim3(32, 4, 4), 256, 0, stream>>>(x, A2, out, out, t);
    }
}